// Round 16
// baseline (357.342 us; speedup 1.0000x reference)
//
#include <hip/hip_runtime.h>

typedef unsigned int uint;
typedef unsigned short ushort;
using short8 = __attribute__((ext_vector_type(8))) short;
using f32x4  = __attribute__((ext_vector_type(4))) float;
using uint4v = __attribute__((ext_vector_type(4))) uint;

#define SCALE_ 0.17677669529663687f
#define MFMA(a,b,c) __builtin_amdgcn_mfma_f32_16x16x32_bf16(a,b,c,0,0,0)

__device__ inline ushort f2bf(float f){
  uint u = __float_as_uint(f);
  return (ushort)((u + 0x7fffu + ((u >> 16) & 1u)) >> 16);
}
__device__ inline uint pk2(float a, float b){
  return (uint)f2bf(a) | ((uint)f2bf(b) << 16);
}
// tanh-form GELU via sigmoid: err <= ~5e-4, far below bf16-hid rounding.
__device__ inline float gelu(float v){
  return v / (1.f + __expf(-1.5957691f * (v + 0.044715f * v * v * v)));
}

// ---------------------------------------------------------------------------
// prep: bf16 weights (SCALE folded into q), scaled qkv bias, bias+mask table
// T2b[cls][h][tok][key] in BF16 (pad = -30000 so padding self-masks).
// ---------------------------------------------------------------------------
__global__ __launch_bounds__(256) void prep_kernel(
    const float* __restrict__ qkv_w, const float* __restrict__ qkv_b,
    const float* __restrict__ rpb, const float* __restrict__ proj_w,
    const float* __restrict__ fc1_w, const float* __restrict__ fc2_w,
    ushort* __restrict__ qkv_wb, float* __restrict__ qkv_bs,
    ushort* __restrict__ proj_wb, ushort* __restrict__ fc1_wb,
    ushort* __restrict__ fc2_wb, ushort* __restrict__ T2b)
{
  int i = blockIdx.x * 256 + threadIdx.x;           // 0..65535
  if (i < 49152) qkv_wb[i] = f2bf(qkv_w[i] * (i < 16384 ? SCALE_ : 1.f));
  if (i < 16384) proj_wb[i] = f2bf(proj_w[i]);
  if (i < 65536) { fc1_wb[i] = f2bf(fc1_w[i]); fc2_wb[i] = f2bf(fc2_w[i]); }
  if (i < 384)   qkv_bs[i] = qkv_b[i] * (i < 128 ? SCALE_ : 1.f);
  if (i < 65536) {
    int cls = i >> 14, h = (i >> 12) & 3, tok = (i >> 6) & 63, key = i & 63;
    float val = -30000.f;
    if (tok < 49 && key < 49) {
      int ri = tok / 7, ci = tok - ri * 7, rj = key / 7, cj = key - rj * 7;
      val = rpb[((ri - rj + 6) * 13 + (ci - cj + 6)) * 4 + h];
      int er = cls >> 1, ec = cls & 1;
      int regi = (er ? (ri < 4 ? 1 : 2) : 0) * 3 + (ec ? (ci < 4 ? 1 : 2) : 0);
      int regj = (er ? (rj < 4 ? 1 : 2) : 0) * 3 + (ec ? (cj < 4 ? 1 : 2) : 0);
      if (regi != regj) val -= 100.f;
    }
    T2b[i] = f2bf(val);
  }
}

// ---------------------------------------------------------------------------
// attn v8.1: m-OUTER with IMMEDIATE per-m oa store (oa in its own LDS region,
// no xls alias) -> oacc is transient (8 regs), one fewer barrier.
// LDS 33792 B: xls [0,16384) | oa [16384,33792); Rp fp32 [0,25088) after B3.
// 4096 blocks, 256 threads, wave w = head w.
// ---------------------------------------------------------------------------
__global__ __launch_bounds__(256, 2) void attn_kernel(
    const float* __restrict__ x, const float* __restrict__ g1, const float* __restrict__ b1,
    const ushort* __restrict__ qkv_wb, const float* __restrict__ qkv_bs,
    const ushort* __restrict__ T2b, const ushort* __restrict__ proj_wb,
    const float* __restrict__ proj_b, float* __restrict__ x_new)
{
  __shared__ __align__(16) char smem[33792];
  char*   xls = smem;                       // [0,16384)
  ushort* oa  = (ushort*)(smem + 16384);    // [16384,33792)  bf16 [64][136]
  float*  Rp  = (float*)smem;               // [0,25088) after B3 (xls+oa-head dead)
  const int tid = threadIdx.x;
  const int w = tid >> 6, lane = tid & 63;
  const int g = lane >> 4, li = lane & 15;
  const int blk = blockIdx.x;
  const int b = blk >> 6, wi = blk & 63;
  const int wr = wi >> 3, wc = wi & 7;
  const float* xb = x + (size_t)b * (3136 * 128);
  const f32x4 zf = {0.f, 0.f, 0.f, 0.f};
  const int srcA = ((g & 1) << 5) + li;
  const int srcB = srcA + 16;
  const int hi = g >> 1;

  // ---- P0: coalesced shifted gather + fp32 LN1 -> xls bf16 (swizzled) ----
#pragma unroll
  for (int it = 0; it < 7; ++it) {
    int gi = it * 256 + tid;
    bool ok = gi < 1568;
    int t = ok ? (gi >> 5) : 48;
    int ch4 = (gi & 31) << 2;
    int tr = t / 7, tc = t - tr * 7;
    int rr = wr * 7 + tr + 3; rr -= (rr >= 56) ? 56 : 0;
    int cc = wc * 7 + tc + 3; cc -= (cc >= 56) ? 56 : 0;
    float4 v = *(const float4*)(xb + (size_t)(rr * 56 + cc) * 128 + ch4);
    float s = v.x + v.y + v.z + v.w;
    float s2 = v.x*v.x + v.y*v.y + v.z*v.z + v.w*v.w;
#pragma unroll
    for (int off = 16; off; off >>= 1) { s += __shfl_xor(s, off); s2 += __shfl_xor(s2, off); }
    float mn = s * 0.0078125f;
    float rs = rsqrtf(s2 * 0.0078125f - mn * mn + 1e-5f);
    if (ok) {
      float4 gg = *(const float4*)(g1 + ch4);
      float4 bb = *(const float4*)(b1 + ch4);
      uint2 u;
      u.x = pk2((v.x - mn) * rs * gg.x + bb.x, (v.y - mn) * rs * gg.y + bb.y);
      u.y = pk2((v.z - mn) * rs * gg.z + bb.z, (v.w - mn) * rs * gg.w + bb.w);
      int slot = ch4 >> 3;
      int tokx = t ^ ((slot & 7) << 1);
      *(uint2*)(xls + (slot * 64 + tokx) * 16 + ((ch4 & 4) << 1)) = u;
    }
  }
  if (tid < 240) {   // zero pad tokens 49..63
    int slot = tid & 15, t = 49 + (tid >> 4);
    int tokx = t ^ ((slot & 7) << 1);
    uint4 z = make_uint4(0u, 0u, 0u, 0u);
    *(uint4*)(xls + (slot * 64 + tokx) * 16) = z;
  }
  __syncthreads();                                  // B0: xls ready

  // ---- P1-k: k MFMA (swapped) -> kf fragments (32 acc transient) ----
  short8 kf[4];
  {
    f32x4 kacc[2][4];
#pragma unroll
    for (int cf = 0; cf < 2; ++cf)
#pragma unroll
      for (int m = 0; m < 4; ++m) kacc[cf][m] = zf;
#pragma unroll
    for (int kt = 0; kt < 4; ++kt) {
      const int slot = kt * 4 + g;
      short8 xf[4];
#pragma unroll
      for (int m = 0; m < 4; ++m)
        xf[m] = *(const short8*)(xls + (slot * 64 + ((m * 16 + li) ^ ((slot & 7) << 1))) * 16);
      const int wofs = kt * 32 + g * 8;
#pragma unroll
      for (int cf = 0; cf < 2; ++cf) {
        short8 wk = *(const short8*)(qkv_wb + (size_t)(128 + w * 32 + cf * 16 + li) * 128 + wofs);
#pragma unroll
        for (int m = 0; m < 4; ++m) kacc[cf][m] = MFMA(wk, xf[m], kacc[cf][m]);
      }
    }
    uint2 kp[2][4];
#pragma unroll
    for (int cf = 0; cf < 2; ++cf) {
      f32x4 kb4 = *(const f32x4*)(qkv_bs + 128 + w * 32 + cf * 16 + g * 4);
#pragma unroll
      for (int m = 0; m < 4; ++m) {
        f32x4 kv = kacc[cf][m] + kb4;
        kp[cf][m].x = pk2(kv[0], kv[1]); kp[cf][m].y = pk2(kv[2], kv[3]);
      }
    }
#pragma unroll
    for (int n = 0; n < 4; ++n) {
      uint a0 = __shfl(kp[0][n].x, srcA), a1 = __shfl(kp[0][n].y, srcA);
      uint a2 = __shfl(kp[0][n].x, srcB), a3 = __shfl(kp[0][n].y, srcB);
      uint b0 = __shfl(kp[1][n].x, srcA), b1 = __shfl(kp[1][n].y, srcA);
      uint b2 = __shfl(kp[1][n].x, srcB), b3 = __shfl(kp[1][n].y, srcB);
      uint4v u = { hi ? b0 : a0, hi ? b1 : a1, hi ? b2 : a2, hi ? b3 : a3 };
      kf[n] = __builtin_bit_cast(short8, u);
    }
  }

  // ---- P1-v: v MFMA -> vt A-fragments directly (32 acc transient) ----
  short8 vt[2][2];
  {
    f32x4 vacc[4][2];
#pragma unroll
    for (int m = 0; m < 4; ++m) { vacc[m][0] = zf; vacc[m][1] = zf; }
#pragma unroll
    for (int kt = 0; kt < 4; ++kt) {
      const int slot = kt * 4 + g;
      short8 xf[4];
#pragma unroll
      for (int m = 0; m < 4; ++m)
        xf[m] = *(const short8*)(xls + (slot * 64 + ((m * 16 + li) ^ ((slot & 7) << 1))) * 16);
      const int wofs = kt * 32 + g * 8;
#pragma unroll
      for (int cf = 0; cf < 2; ++cf) {
        short8 wv = *(const short8*)(qkv_wb + (size_t)(256 + w * 32 + cf * 16 + li) * 128 + wofs);
#pragma unroll
        for (int m = 0; m < 4; ++m) vacc[m][cf] = MFMA(xf[m], wv, vacc[m][cf]);
      }
    }
    uint2 vp[4][2];
#pragma unroll
    for (int cf = 0; cf < 2; ++cf) {
      float vb = qkv_bs[256 + w * 32 + cf * 16 + li];
#pragma unroll
      for (int m = 0; m < 4; ++m) {
        f32x4 vv = vacc[m][cf];
        vp[m][cf].x = pk2(vv[0] + vb, vv[1] + vb);
        vp[m][cf].y = pk2(vv[2] + vb, vv[3] + vb);
      }
    }
#pragma unroll
    for (int kt = 0; kt < 2; ++kt)
#pragma unroll
      for (int half = 0; half < 2; ++half) {
        uint a0 = __shfl(vp[kt * 2][half].x, srcA), a1 = __shfl(vp[kt * 2][half].y, srcA);
        uint a2 = __shfl(vp[kt * 2][half].x, srcB), a3 = __shfl(vp[kt * 2][half].y, srcB);
        uint b0 = __shfl(vp[kt * 2 + 1][half].x, srcA), b1 = __shfl(vp[kt * 2 + 1][half].y, srcA);
        uint b2 = __shfl(vp[kt * 2 + 1][half].x, srcB), b3 = __shfl(vp[kt * 2 + 1][half].y, srcB);
        uint4v uv = { hi ? b0 : a0, hi ? b1 : a1, hi ? b2 : a2, hi ? b3 : a3 };
        vt[kt][half] = __builtin_bit_cast(short8, uv);
      }
  }

  // ---- P2: per-m {q MFMA, scores, softmax, PV, IMMEDIATE oa store} ----
  {
    const int cls = ((wr == 7) ? 2 : 0) | ((wc == 7) ? 1 : 0);
    const ushort* Tb = T2b + ((cls * 4 + w) << 12);
    const f32x4 qb40 = *(const f32x4*)(qkv_bs + w * 32 + g * 4);
    const f32x4 qb41 = *(const f32x4*)(qkv_bs + w * 32 + 16 + g * 4);
#pragma unroll
    for (int m = 0; m < 4; ++m) {
      // q MFMA for this m only (8 acc live)
      f32x4 qacc[2] = {zf, zf};
#pragma unroll
      for (int kt = 0; kt < 4; ++kt) {
        const int slot = kt * 4 + g;
        short8 xfm = *(const short8*)(xls + (slot * 64 + ((m * 16 + li) ^ ((slot & 7) << 1))) * 16);
        const int wofs = kt * 32 + g * 8;
        short8 wq0 = *(const short8*)(qkv_wb + (size_t)(w * 32 + li) * 128 + wofs);
        short8 wq1 = *(const short8*)(qkv_wb + (size_t)(w * 32 + 16 + li) * 128 + wofs);
        qacc[0] = MFMA(wq0, xfm, qacc[0]);
        qacc[1] = MFMA(wq1, xfm, qacc[1]);
      }
      uint2 qpm[2];
      {
        f32x4 q0 = qacc[0] + qb40;
        f32x4 q1 = qacc[1] + qb41;
        qpm[0].x = pk2(q0[0], q0[1]); qpm[0].y = pk2(q0[2], q0[3]);
        qpm[1].x = pk2(q1[0], q1[1]); qpm[1].y = pk2(q1[2], q1[3]);
      }
      uint a0 = __shfl(qpm[0].x, srcA), a1 = __shfl(qpm[0].y, srcA);
      uint a2 = __shfl(qpm[0].x, srcB), a3 = __shfl(qpm[0].y, srcB);
      uint b0 = __shfl(qpm[1].x, srcA), b1 = __shfl(qpm[1].y, srcA);
      uint b2 = __shfl(qpm[1].x, srcB), b3 = __shfl(qpm[1].y, srcB);
      uint4v uq = { hi ? b0 : a0, hi ? b1 : a1, hi ? b2 : a2, hi ? b3 : a3 };
      short8 qf = __builtin_bit_cast(short8, uq);
      // scores + bf16 bias table
      f32x4 s[4];
#pragma unroll
      for (int n = 0; n < 4; ++n) {
        s[n] = MFMA(kf[n], qf, zf);
        uint2 tv = *(const uint2*)(Tb + (m * 16 + li) * 64 + n * 16 + g * 4);
        s[n][0] += __uint_as_float(tv.x << 16);
        s[n][1] += __uint_as_float(tv.x & 0xffff0000u);
        s[n][2] += __uint_as_float(tv.y << 16);
        s[n][3] += __uint_as_float(tv.y & 0xffff0000u);
      }
      // softmax (row in-thread over n, 16-lane group reduce over cols)
      float mx = -3.4e38f;
#pragma unroll
      for (int n = 0; n < 4; ++n)
        mx = fmaxf(mx, fmaxf(fmaxf(s[n][0], s[n][1]), fmaxf(s[n][2], s[n][3])));
      mx = fmaxf(mx, __shfl_xor(mx, 16));
      mx = fmaxf(mx, __shfl_xor(mx, 32));
      float sum = 0.f;
#pragma unroll
      for (int n = 0; n < 4; ++n)
#pragma unroll
        for (int r = 0; r < 4; ++r) { float e = __expf(s[n][r] - mx); s[n][r] = e; sum += e; }
      sum += __shfl_xor(sum, 16); sum += __shfl_xor(sum, 32);
      float rsm = 1.f / sum;
      uint um[4][2];
#pragma unroll
      for (int n = 0; n < 4; ++n) {
        um[n][0] = pk2(s[n][0] * rsm, s[n][1] * rsm);
        um[n][1] = pk2(s[n][2] * rsm, s[n][3] * rsm);
      }
      // PV for this m -> transient oacc -> immediate oa store
      f32x4 oacc[2] = {zf, zf};
#pragma unroll
      for (int kt = 0; kt < 2; ++kt) {
        uint t00 = __shfl(um[kt * 2][0], srcA),  t10 = __shfl(um[kt * 2 + 1][0], srcA);
        uint t01 = __shfl(um[kt * 2][1], srcA),  t11 = __shfl(um[kt * 2 + 1][1], srcA);
        uint t02 = __shfl(um[kt * 2][0], srcB),  t12 = __shfl(um[kt * 2 + 1][0], srcB);
        uint t03 = __shfl(um[kt * 2][1], srcB),  t13 = __shfl(um[kt * 2 + 1][1], srcB);
        uint4v pu = { hi ? t10 : t00, hi ? t11 : t01, hi ? t12 : t02, hi ? t13 : t03 };
        short8 pf = __builtin_bit_cast(short8, pu);
        oacc[0] = MFMA(vt[kt][0], pf, oacc[0]);
        oacc[1] = MFMA(vt[kt][1], pf, oacc[1]);
      }
#pragma unroll
      for (int cf = 0; cf < 2; ++cf) {
        uint2 ou; ou.x = pk2(oacc[cf][0], oacc[cf][1]);
        ou.y = pk2(oacc[cf][2], oacc[cf][3]);
        *(uint2*)((char*)oa + ((m * 16 + li) * 136 + w * 32 + cf * 16 + g * 4) * 2) = ou;
      }
    }
  }
  __syncthreads();                                  // B2: oa ready

  // ---- P3: proj MFMA (wave w owns out-ch [32w,32w+32)) ----
  f32x4 pacc[2][4];
#pragma unroll
  for (int cf = 0; cf < 2; ++cf)
#pragma unroll
    for (int m = 0; m < 4; ++m) pacc[cf][m] = zf;
#pragma unroll
  for (int kt = 0; kt < 4; ++kt) {
    short8 af[4];
#pragma unroll
    for (int m = 0; m < 4; ++m)
      af[m] = *(const short8*)((char*)oa + (m * 16 + li) * 272 + kt * 64 + g * 16);
#pragma unroll
    for (int cf = 0; cf < 2; ++cf) {
      short8 wp = *(const short8*)(proj_wb + (size_t)(w * 32 + cf * 16 + li) * 128 + kt * 32 + g * 8);
#pragma unroll
      for (int m = 0; m < 4; ++m) pacc[cf][m] = MFMA(af[m], wp, pacc[cf][m]);
    }
  }
  __syncthreads();                                  // B3: oa reads done
#pragma unroll
  for (int cf = 0; cf < 2; ++cf) {
    int col = w * 32 + cf * 16 + li;
    float pb = proj_b[col];
#pragma unroll
    for (int m = 0; m < 4; ++m)
#pragma unroll
      for (int r = 0; r < 4; ++r) {
        int t2 = m * 16 + g * 4 + r;
        if (t2 < 49)
          Rp[t2 * 128 + (col ^ ((t2 & 7) << 2))] = pacc[cf][m][r] + pb;
      }
  }
  __syncthreads();                                  // B4: Rp ready

  // ---- P4: coalesced residual epilogue ----
#pragma unroll
  for (int it = 0; it < 7; ++it) {
    int gi = it * 256 + tid;
    if (gi < 1568) {
      int t = gi >> 5, ch4 = (gi & 31) << 2;
      int tr = t / 7, tc = t - tr * 7;
      int rr = wr * 7 + tr + 3; rr -= (rr >= 56) ? 56 : 0;
      int cc = wc * 7 + tc + 3; cc -= (cc >= 56) ? 56 : 0;
      size_t off = ((size_t)b * 3136 + rr * 56 + cc) * 128 + ch4;
      f32x4 d = *(const f32x4*)&Rp[t * 128 + (ch4 ^ ((t & 7) << 2))];
      float4 xr = *(const float4*)(x + off);
      float4 ov;
      ov.x = xr.x + d[0]; ov.y = xr.y + d[1];
      ov.z = xr.z + d[2]; ov.w = xr.w + d[3];
      *(float4*)(x_new + off) = ov;
    }
  }
}

// ---------------------------------------------------------------------------
// fused MLP v6 (unchanged from R15): cooperative 64-row block, 4 waves,
// oi-INNER MFMA1, double-buffered hid, cheap sigmoid-form GELU.
// ---------------------------------------------------------------------------
__global__ __launch_bounds__(256, 2) void mlp_kernel(
    float* __restrict__ xio,
    const float* __restrict__ g2, const float* __restrict__ b2,
    const ushort* __restrict__ w1, const float* __restrict__ fb1,
    const ushort* __restrict__ w2, const float* __restrict__ fb2)
{
  __shared__ __align__(16) char smem[49152];   // Axs 16K | hid0 16K | hid1 16K
  char* Axs = smem;
  float* Rp = (float*)smem;                    // [64][128] fp32, aliases Axs+hid0
  const int tid = threadIdx.x, lane = tid & 63, w = tid >> 6;
  const int g = lane >> 4, li = lane & 15;
  float* xw = xio + (size_t)blockIdx.x * 64 * 128;
  const f32x4 zf = {0.f, 0.f, 0.f, 0.f};

  // ---- stage: LN2(x) -> Axs bf16 [16 chslot][64 tok][16B], tok-xor swizzle --
#pragma unroll
  for (int it = 0; it < 8; ++it) {
    int gi = it * 256 + tid;
    int row = gi >> 5, ch4 = (gi & 31) << 2;
    float4 v = *(const float4*)(xw + row * 128 + ch4);
    float s = v.x + v.y + v.z + v.w;
    float s2 = v.x*v.x + v.y*v.y + v.z*v.z + v.w*v.w;
#pragma unroll
    for (int off = 16; off; off >>= 1) { s += __shfl_xor(s, off); s2 += __shfl_xor(s2, off); }
    float mn = s * 0.0078125f;
    float rs = rsqrtf(s2 * 0.0078125f - mn * mn + 1e-5f);
    float4 gg = *(const float4*)(g2 + ch4);
    float4 bb = *(const float4*)(b2 + ch4);
    uint2 u;
    u.x = pk2((v.x - mn) * rs * gg.x + bb.x, (v.y - mn) * rs * gg.y + bb.y);
    u.y = pk2((v.z - mn) * rs * gg.z + bb.z, (v.w - mn) * rs * gg.w + bb.w);
    int slot = ch4 >> 3;
    int tokx = row ^ ((slot & 7) << 1);
    *(uint2*)(Axs + (slot * 64 + tokx) * 16 + ((ch4 & 4) << 1)) = u;
  }
  __syncthreads();                   // S0: Axs ready

  f32x4 acc2[4][2];
#pragma unroll
  for (int mi = 0; mi < 4; ++mi) { acc2[mi][0] = zf; acc2[mi][1] = zf; }

  for (int ck = 0; ck < 4; ++ck) {
    char* hls = smem + 16384 + ((ck & 1) << 14);   // double buffer
    // ---- MFMA1: hid_c[och 32 (this wave)][tok 64] = W1 slice @ LN2(x)^T ----
    f32x4 acc1[2][4];
#pragma unroll
    for (int oi = 0; oi < 2; ++oi)
#pragma unroll
      for (int mi = 0; mi < 4; ++mi) acc1[oi][mi] = zf;
#pragma unroll
    for (int kt = 0; kt < 4; ++kt) {
      const int slot = kt * 4 + g;
      short8 xf[4];
#pragma unroll
      for (int mi = 0; mi < 4; ++mi)
        xf[mi] = *(const short8*)(Axs + (slot * 64 + ((mi * 16 + li) ^ ((slot & 7) << 1))) * 16);
#pragma unroll
      for (int oi = 0; oi < 2; ++oi) {
        short8 wf = *(const short8*)(w1 + (size_t)(ck * 128 + w * 32 + oi * 16 + li) * 128 + kt * 32 + g * 8);
#pragma unroll
        for (int mi = 0; mi < 4; ++mi) acc1[oi][mi] = MFMA(wf, xf[mi], acc1[oi][mi]);
      }
    }
#pragma unroll
    for (int oi = 0; oi < 2; ++oi) {
      f32x4 b4 = *(const f32x4*)(fb1 + ck * 128 + w * 32 + oi * 16 + g * 4);
#pragma unroll
      for (int mi = 0; mi < 4; ++mi) {
        f32x4 h = acc1[oi][mi] + b4;
        uint2 u; u.x = pk2(gelu(h[0]), gelu(h[1])); u.y = pk2(gelu(h[2]), gelu(h[3]));
        *(uint2*)(hls + ((w * 4 + oi * 2 + (g >> 1)) * 64 + mi * 16 + li) * 16 + ((g & 1) << 3)) = u;
      }
    }
    __syncthreads();                 // hid chunk ready (only barrier per ck)
    // ---- MFMA2: acc2[tok 64][out 32 (this wave)] += hid_c @ W2 slice^T ----
#pragma unroll
    for (int kt = 0; kt < 4; ++kt) {
      short8 hf[4];
#pragma unroll
      for (int mi = 0; mi < 4; ++mi)
        hf[mi] = *(const short8*)(hls + ((kt * 4 + g) * 64 + mi * 16 + li) * 16);
#pragma unroll
      for (int bo = 0; bo < 2; ++bo) {
        short8 wf = *(const short8*)(w2 + (size_t)(w * 32 + bo * 16 + li) * 512 + ck * 128 + kt * 32 + g * 8);
#pragma unroll
        for (int mi = 0; mi < 4; ++mi) acc2[mi][bo] = MFMA(hf[mi], wf, acc2[mi][bo]);
      }
    }
    // next ck writes the OTHER hid buffer -> no trailing barrier needed
  }

  // ---- epilogue: fp32 repack + residual ----
#pragma unroll
  for (int mi = 0; mi < 4; ++mi)
#pragma unroll
    for (int bo = 0; bo < 2; ++bo) {
      int out = w * 32 + bo * 16 + li;
#pragma unroll
      for (int r = 0; r < 4; ++r) {
        int tok = mi * 16 + g * 4 + r;
        Rp[tok * 128 + (out ^ ((tok & 7) << 2))] = acc2[mi][bo][r];
      }
    }
  __syncthreads();                   // Rp ready
#pragma unroll
  for (int it = 0; it < 8; ++it) {
    int gi = it * 256 + tid;
    int row = gi >> 5, ch4 = (gi & 31) << 2;
    f32x4 d = *(const f32x4*)&Rp[row * 128 + (ch4 ^ ((row & 7) << 2))];
    float4 xr = *(const float4*)(xw + row * 128 + ch4);
    float4 bb = *(const float4*)(fb2 + ch4);
    float4 ov;
    ov.x = xr.x + d[0] + bb.x; ov.y = xr.y + d[1] + bb.y;
    ov.z = xr.z + d[2] + bb.z; ov.w = xr.w + d[3] + bb.w;
    *(float4*)(xw + row * 128 + ch4) = ov;
  }
}

// ---------------------------------------------------------------------------
extern "C" void kernel_launch(void* const* d_in, const int* in_sizes, int n_in,
                              void* d_out, int out_size, void* d_ws, size_t ws_size,
                              hipStream_t stream)
{
  const float* x      = (const float*)d_in[0];
  const float* g1     = (const float*)d_in[1];
  const float* b1     = (const float*)d_in[2];
  const float* qkv_w  = (const float*)d_in[3];
  const float* qkv_b  = (const float*)d_in[4];
  const float* rpb    = (const float*)d_in[5];
  const float* proj_w = (const float*)d_in[6];
  const float* proj_b = (const float*)d_in[7];
  const float* g2     = (const float*)d_in[8];
  const float* b2     = (const float*)d_in[9];
  const float* fc1_w  = (const float*)d_in[10];
  const float* fc1_b  = (const float*)d_in[11];
  const float* fc2_w  = (const float*)d_in[12];
  const float* fc2_b  = (const float*)d_in[13];

  char* ws = (char*)d_ws;
  ushort* T2b     = (ushort*)ws;                // 131072 B
  ushort* qkv_wb  = (ushort*)(ws + 262144);     // 98304
  ushort* proj_wb = (ushort*)(ws + 360448);     // 32768
  ushort* fc1_wb  = (ushort*)(ws + 393216);     // 131072
  ushort* fc2_wb  = (ushort*)(ws + 524288);     // 131072
  float*  qkv_bs  = (float*)(ws + 655360);      // 1536
  float* out = (float*)d_out;                   // x_new lives here too

  prep_kernel<<<256, 256, 0, stream>>>(qkv_w, qkv_b, rpb, proj_w, fc1_w, fc2_w,
                                       qkv_wb, qkv_bs, proj_wb, fc1_wb, fc2_wb, T2b);
  attn_kernel<<<4096, 256, 0, stream>>>(x, g1, b1, qkv_wb, qkv_bs, T2b,
                                        proj_wb, proj_b, out);
  mlp_kernel<<<3136, 256, 0, stream>>>(out, g2, b2, fc1_wb, fc1_b, fc2_wb, fc2_b);
}

// Round 17
// 305.438 us; speedup vs baseline: 1.1699x; 1.1699x over previous
//
#include <hip/hip_runtime.h>

typedef unsigned int uint;
typedef unsigned short ushort;
using short8 = __attribute__((ext_vector_type(8))) short;
using f32x4  = __attribute__((ext_vector_type(4))) float;
using uint4v = __attribute__((ext_vector_type(4))) uint;

#define SCALE_ 0.17677669529663687f
#define MFMA(a,b,c) __builtin_amdgcn_mfma_f32_16x16x32_bf16(a,b,c,0,0,0)

__device__ inline ushort f2bf(float f){
  uint u = __float_as_uint(f);
  return (ushort)((u + 0x7fffu + ((u >> 16) & 1u)) >> 16);
}
__device__ inline uint pk2(float a, float b){
  return (uint)f2bf(a) | ((uint)f2bf(b) << 16);
}
// tanh-form GELU via sigmoid: err <= ~5e-4, far below bf16-hid rounding.
__device__ inline float gelu(float v){
  return v / (1.f + __expf(-1.5957691f * (v + 0.044715f * v * v * v)));
}

// ---------------------------------------------------------------------------
// prep: bf16 weights (SCALE folded into q), scaled qkv bias, bias+mask table
// T2b[cls][h][tok][key] in BF16 (pad = -30000 so padding self-masks).
// ---------------------------------------------------------------------------
__global__ __launch_bounds__(256) void prep_kernel(
    const float* __restrict__ qkv_w, const float* __restrict__ qkv_b,
    const float* __restrict__ rpb, const float* __restrict__ proj_w,
    const float* __restrict__ fc1_w, const float* __restrict__ fc2_w,
    ushort* __restrict__ qkv_wb, float* __restrict__ qkv_bs,
    ushort* __restrict__ proj_wb, ushort* __restrict__ fc1_wb,
    ushort* __restrict__ fc2_wb, ushort* __restrict__ T2b)
{
  int i = blockIdx.x * 256 + threadIdx.x;           // 0..65535
  if (i < 49152) qkv_wb[i] = f2bf(qkv_w[i] * (i < 16384 ? SCALE_ : 1.f));
  if (i < 16384) proj_wb[i] = f2bf(proj_w[i]);
  if (i < 65536) { fc1_wb[i] = f2bf(fc1_w[i]); fc2_wb[i] = f2bf(fc2_w[i]); }
  if (i < 384)   qkv_bs[i] = qkv_b[i] * (i < 128 ? SCALE_ : 1.f);
  if (i < 65536) {
    int cls = i >> 14, h = (i >> 12) & 3, tok = (i >> 6) & 63, key = i & 63;
    float val = -30000.f;
    if (tok < 49 && key < 49) {
      int ri = tok / 7, ci = tok - ri * 7, rj = key / 7, cj = key - rj * 7;
      val = rpb[((ri - rj + 6) * 13 + (ci - cj + 6)) * 4 + h];
      int er = cls >> 1, ec = cls & 1;
      int regi = (er ? (ri < 4 ? 1 : 2) : 0) * 3 + (ec ? (ci < 4 ? 1 : 2) : 0);
      int regj = (er ? (rj < 4 ? 1 : 2) : 0) * 3 + (ec ? (cj < 4 ? 1 : 2) : 0);
      if (regi != regj) val -= 100.f;
    }
    T2b[i] = f2bf(val);
  }
}

// ---------------------------------------------------------------------------
// attn v8 (best measured): m-OUTER, kf+vt once, per-m
// {q-MFMA, scores, softmax, PV}.  T2 bf16.  LDS 25088 B.
// 4096 blocks, 256 threads, wave w = head w.
// ---------------------------------------------------------------------------
__global__ __launch_bounds__(256, 2) void attn_kernel(
    const float* __restrict__ x, const float* __restrict__ g1, const float* __restrict__ b1,
    const ushort* __restrict__ qkv_wb, const float* __restrict__ qkv_bs,
    const ushort* __restrict__ T2b, const ushort* __restrict__ proj_wb,
    const float* __restrict__ proj_b, float* __restrict__ x_new)
{
  __shared__ __align__(16) char smem[25088];
  char*   xls = smem;                 // [0,16384)  staged LN1-x (subtiled+swz)
  ushort* oa  = (ushort*)smem;        // [0,17408)  after B1 (xls dead)
  float*  Rp  = (float*)smem;         // [0,25088)  after B3 (oa dead)
  const int tid = threadIdx.x;
  const int w = tid >> 6, lane = tid & 63;
  const int g = lane >> 4, li = lane & 15;
  const int blk = blockIdx.x;
  const int b = blk >> 6, wi = blk & 63;
  const int wr = wi >> 3, wc = wi & 7;
  const float* xb = x + (size_t)b * (3136 * 128);
  const f32x4 zf = {0.f, 0.f, 0.f, 0.f};
  const int srcA = ((g & 1) << 5) + li;
  const int srcB = srcA + 16;
  const int hi = g >> 1;

  // ---- P0: coalesced shifted gather + fp32 LN1 -> xls bf16 (swizzled) ----
#pragma unroll
  for (int it = 0; it < 7; ++it) {
    int gi = it * 256 + tid;
    bool ok = gi < 1568;
    int t = ok ? (gi >> 5) : 48;
    int ch4 = (gi & 31) << 2;
    int tr = t / 7, tc = t - tr * 7;
    int rr = wr * 7 + tr + 3; rr -= (rr >= 56) ? 56 : 0;
    int cc = wc * 7 + tc + 3; cc -= (cc >= 56) ? 56 : 0;
    float4 v = *(const float4*)(xb + (size_t)(rr * 56 + cc) * 128 + ch4);
    float s = v.x + v.y + v.z + v.w;
    float s2 = v.x*v.x + v.y*v.y + v.z*v.z + v.w*v.w;
#pragma unroll
    for (int off = 16; off; off >>= 1) { s += __shfl_xor(s, off); s2 += __shfl_xor(s2, off); }
    float mn = s * 0.0078125f;
    float rs = rsqrtf(s2 * 0.0078125f - mn * mn + 1e-5f);
    if (ok) {
      float4 gg = *(const float4*)(g1 + ch4);
      float4 bb = *(const float4*)(b1 + ch4);
      uint2 u;
      u.x = pk2((v.x - mn) * rs * gg.x + bb.x, (v.y - mn) * rs * gg.y + bb.y);
      u.y = pk2((v.z - mn) * rs * gg.z + bb.z, (v.w - mn) * rs * gg.w + bb.w);
      int slot = ch4 >> 3;
      int tokx = t ^ ((slot & 7) << 1);
      *(uint2*)(xls + (slot * 64 + tokx) * 16 + ((ch4 & 4) << 1)) = u;
    }
  }
  if (tid < 240) {   // zero pad tokens 49..63
    int slot = tid & 15, t = 49 + (tid >> 4);
    int tokx = t ^ ((slot & 7) << 1);
    uint4 z = make_uint4(0u, 0u, 0u, 0u);
    *(uint4*)(xls + (slot * 64 + tokx) * 16) = z;
  }
  __syncthreads();                                  // B0: xls ready

  // ---- P1-k: k MFMA (swapped) -> kf fragments (32 acc transient) ----
  short8 kf[4];
  {
    f32x4 kacc[2][4];
#pragma unroll
    for (int cf = 0; cf < 2; ++cf)
#pragma unroll
      for (int m = 0; m < 4; ++m) kacc[cf][m] = zf;
#pragma unroll
    for (int kt = 0; kt < 4; ++kt) {
      const int slot = kt * 4 + g;
      short8 xf[4];
#pragma unroll
      for (int m = 0; m < 4; ++m)
        xf[m] = *(const short8*)(xls + (slot * 64 + ((m * 16 + li) ^ ((slot & 7) << 1))) * 16);
      const int wofs = kt * 32 + g * 8;
#pragma unroll
      for (int cf = 0; cf < 2; ++cf) {
        short8 wk = *(const short8*)(qkv_wb + (size_t)(128 + w * 32 + cf * 16 + li) * 128 + wofs);
#pragma unroll
        for (int m = 0; m < 4; ++m) kacc[cf][m] = MFMA(wk, xf[m], kacc[cf][m]);
      }
    }
    uint2 kp[2][4];
#pragma unroll
    for (int cf = 0; cf < 2; ++cf) {
      f32x4 kb4 = *(const f32x4*)(qkv_bs + 128 + w * 32 + cf * 16 + g * 4);
#pragma unroll
      for (int m = 0; m < 4; ++m) {
        f32x4 kv = kacc[cf][m] + kb4;
        kp[cf][m].x = pk2(kv[0], kv[1]); kp[cf][m].y = pk2(kv[2], kv[3]);
      }
    }
#pragma unroll
    for (int n = 0; n < 4; ++n) {
      uint a0 = __shfl(kp[0][n].x, srcA), a1 = __shfl(kp[0][n].y, srcA);
      uint a2 = __shfl(kp[0][n].x, srcB), a3 = __shfl(kp[0][n].y, srcB);
      uint b0 = __shfl(kp[1][n].x, srcA), b1 = __shfl(kp[1][n].y, srcA);
      uint b2 = __shfl(kp[1][n].x, srcB), b3 = __shfl(kp[1][n].y, srcB);
      uint4v u = { hi ? b0 : a0, hi ? b1 : a1, hi ? b2 : a2, hi ? b3 : a3 };
      kf[n] = __builtin_bit_cast(short8, u);
    }
  }

  // ---- P1-v: v MFMA -> vt A-fragments directly (32 acc transient) ----
  short8 vt[2][2];
  {
    f32x4 vacc[4][2];
#pragma unroll
    for (int m = 0; m < 4; ++m) { vacc[m][0] = zf; vacc[m][1] = zf; }
#pragma unroll
    for (int kt = 0; kt < 4; ++kt) {
      const int slot = kt * 4 + g;
      short8 xf[4];
#pragma unroll
      for (int m = 0; m < 4; ++m)
        xf[m] = *(const short8*)(xls + (slot * 64 + ((m * 16 + li) ^ ((slot & 7) << 1))) * 16);
      const int wofs = kt * 32 + g * 8;
#pragma unroll
      for (int cf = 0; cf < 2; ++cf) {
        short8 wv = *(const short8*)(qkv_wb + (size_t)(256 + w * 32 + cf * 16 + li) * 128 + wofs);
#pragma unroll
        for (int m = 0; m < 4; ++m) vacc[m][cf] = MFMA(xf[m], wv, vacc[m][cf]);
      }
    }
    uint2 vp[4][2];
#pragma unroll
    for (int cf = 0; cf < 2; ++cf) {
      float vb = qkv_bs[256 + w * 32 + cf * 16 + li];
#pragma unroll
      for (int m = 0; m < 4; ++m) {
        f32x4 vv = vacc[m][cf];
        vp[m][cf].x = pk2(vv[0] + vb, vv[1] + vb);
        vp[m][cf].y = pk2(vv[2] + vb, vv[3] + vb);
      }
    }
#pragma unroll
    for (int kt = 0; kt < 2; ++kt)
#pragma unroll
      for (int half = 0; half < 2; ++half) {
        uint a0 = __shfl(vp[kt * 2][half].x, srcA), a1 = __shfl(vp[kt * 2][half].y, srcA);
        uint a2 = __shfl(vp[kt * 2][half].x, srcB), a3 = __shfl(vp[kt * 2][half].y, srcB);
        uint b0 = __shfl(vp[kt * 2 + 1][half].x, srcA), b1 = __shfl(vp[kt * 2 + 1][half].y, srcA);
        uint b2 = __shfl(vp[kt * 2 + 1][half].x, srcB), b3 = __shfl(vp[kt * 2 + 1][half].y, srcB);
        uint4v uv = { hi ? b0 : a0, hi ? b1 : a1, hi ? b2 : a2, hi ? b3 : a3 };
        vt[kt][half] = __builtin_bit_cast(short8, uv);
      }
  }

  // ---- P2: per-m {q MFMA, scores, softmax, PV}  (small transient state) ----
  f32x4 oacc[2][4];
#pragma unroll
  for (int cf = 0; cf < 2; ++cf)
#pragma unroll
    for (int m = 0; m < 4; ++m) oacc[cf][m] = zf;
  {
    const int cls = ((wr == 7) ? 2 : 0) | ((wc == 7) ? 1 : 0);
    const ushort* Tb = T2b + ((cls * 4 + w) << 12);
    const f32x4 qb40 = *(const f32x4*)(qkv_bs + w * 32 + g * 4);
    const f32x4 qb41 = *(const f32x4*)(qkv_bs + w * 32 + 16 + g * 4);
#pragma unroll
    for (int m = 0; m < 4; ++m) {
      // q MFMA for this m only (8 acc live)
      f32x4 qacc[2] = {zf, zf};
#pragma unroll
      for (int kt = 0; kt < 4; ++kt) {
        const int slot = kt * 4 + g;
        short8 xfm = *(const short8*)(xls + (slot * 64 + ((m * 16 + li) ^ ((slot & 7) << 1))) * 16);
        const int wofs = kt * 32 + g * 8;
        short8 wq0 = *(const short8*)(qkv_wb + (size_t)(w * 32 + li) * 128 + wofs);
        short8 wq1 = *(const short8*)(qkv_wb + (size_t)(w * 32 + 16 + li) * 128 + wofs);
        qacc[0] = MFMA(wq0, xfm, qacc[0]);
        qacc[1] = MFMA(wq1, xfm, qacc[1]);
      }
      uint2 qpm[2];
      {
        f32x4 q0 = qacc[0] + qb40;
        f32x4 q1 = qacc[1] + qb41;
        qpm[0].x = pk2(q0[0], q0[1]); qpm[0].y = pk2(q0[2], q0[3]);
        qpm[1].x = pk2(q1[0], q1[1]); qpm[1].y = pk2(q1[2], q1[3]);
      }
      uint a0 = __shfl(qpm[0].x, srcA), a1 = __shfl(qpm[0].y, srcA);
      uint a2 = __shfl(qpm[0].x, srcB), a3 = __shfl(qpm[0].y, srcB);
      uint b0 = __shfl(qpm[1].x, srcA), b1 = __shfl(qpm[1].y, srcA);
      uint b2 = __shfl(qpm[1].x, srcB), b3 = __shfl(qpm[1].y, srcB);
      uint4v uq = { hi ? b0 : a0, hi ? b1 : a1, hi ? b2 : a2, hi ? b3 : a3 };
      short8 qf = __builtin_bit_cast(short8, uq);
      // scores + bf16 bias table
      f32x4 s[4];
#pragma unroll
      for (int n = 0; n < 4; ++n) {
        s[n] = MFMA(kf[n], qf, zf);
        uint2 tv = *(const uint2*)(Tb + (m * 16 + li) * 64 + n * 16 + g * 4);
        s[n][0] += __uint_as_float(tv.x << 16);
        s[n][1] += __uint_as_float(tv.x & 0xffff0000u);
        s[n][2] += __uint_as_float(tv.y << 16);
        s[n][3] += __uint_as_float(tv.y & 0xffff0000u);
      }
      // softmax (row in-thread over n, 16-lane group reduce over cols)
      float mx = -3.4e38f;
#pragma unroll
      for (int n = 0; n < 4; ++n)
        mx = fmaxf(mx, fmaxf(fmaxf(s[n][0], s[n][1]), fmaxf(s[n][2], s[n][3])));
      mx = fmaxf(mx, __shfl_xor(mx, 16));
      mx = fmaxf(mx, __shfl_xor(mx, 32));
      float sum = 0.f;
#pragma unroll
      for (int n = 0; n < 4; ++n)
#pragma unroll
        for (int r = 0; r < 4; ++r) { float e = __expf(s[n][r] - mx); s[n][r] = e; sum += e; }
      sum += __shfl_xor(sum, 16); sum += __shfl_xor(sum, 32);
      float rsm = 1.f / sum;
      uint um[4][2];
#pragma unroll
      for (int n = 0; n < 4; ++n) {
        um[n][0] = pk2(s[n][0] * rsm, s[n][1] * rsm);
        um[n][1] = pk2(s[n][2] * rsm, s[n][3] * rsm);
      }
      // PV for this m
#pragma unroll
      for (int kt = 0; kt < 2; ++kt) {
        uint t00 = __shfl(um[kt * 2][0], srcA),  t10 = __shfl(um[kt * 2 + 1][0], srcA);
        uint t01 = __shfl(um[kt * 2][1], srcA),  t11 = __shfl(um[kt * 2 + 1][1], srcA);
        uint t02 = __shfl(um[kt * 2][0], srcB),  t12 = __shfl(um[kt * 2 + 1][0], srcB);
        uint t03 = __shfl(um[kt * 2][1], srcB),  t13 = __shfl(um[kt * 2 + 1][1], srcB);
        uint4v pu = { hi ? t10 : t00, hi ? t11 : t01, hi ? t12 : t02, hi ? t13 : t03 };
        short8 pf = __builtin_bit_cast(short8, pu);
        oacc[0][m] = MFMA(vt[kt][0], pf, oacc[0][m]);
        oacc[1][m] = MFMA(vt[kt][1], pf, oacc[1][m]);
      }
    }
  }
  __syncthreads();                                  // B1: xls dead
  // attn-out -> oa[64][136] bf16 (cross-head gather for proj)
#pragma unroll
  for (int cf = 0; cf < 2; ++cf)
#pragma unroll
    for (int m = 0; m < 4; ++m) {
      uint2 ou; ou.x = pk2(oacc[cf][m][0], oacc[cf][m][1]);
      ou.y = pk2(oacc[cf][m][2], oacc[cf][m][3]);
      *(uint2*)((char*)oa + ((m * 16 + li) * 136 + w * 32 + cf * 16 + g * 4) * 2) = ou;
    }
  __syncthreads();                                  // B2: oa ready

  // ---- P3: proj MFMA (wave w owns out-ch [32w,32w+32)) ----
  f32x4 pacc[2][4];
#pragma unroll
  for (int cf = 0; cf < 2; ++cf)
#pragma unroll
    for (int m = 0; m < 4; ++m) pacc[cf][m] = zf;
#pragma unroll
  for (int kt = 0; kt < 4; ++kt) {
    short8 af[4];
#pragma unroll
    for (int m = 0; m < 4; ++m)
      af[m] = *(const short8*)((char*)oa + (m * 16 + li) * 272 + kt * 64 + g * 16);
#pragma unroll
    for (int cf = 0; cf < 2; ++cf) {
      short8 wp = *(const short8*)(proj_wb + (size_t)(w * 32 + cf * 16 + li) * 128 + kt * 32 + g * 8);
#pragma unroll
      for (int m = 0; m < 4; ++m) pacc[cf][m] = MFMA(af[m], wp, pacc[cf][m]);
    }
  }
  __syncthreads();                                  // B3: oa reads done
#pragma unroll
  for (int cf = 0; cf < 2; ++cf) {
    int col = w * 32 + cf * 16 + li;
    float pb = proj_b[col];
#pragma unroll
    for (int m = 0; m < 4; ++m)
#pragma unroll
      for (int r = 0; r < 4; ++r) {
        int t2 = m * 16 + g * 4 + r;
        if (t2 < 49)
          Rp[t2 * 128 + (col ^ ((t2 & 7) << 2))] = pacc[cf][m][r] + pb;
      }
  }
  __syncthreads();                                  // B4: Rp ready

  // ---- P4: coalesced residual epilogue ----
#pragma unroll
  for (int it = 0; it < 7; ++it) {
    int gi = it * 256 + tid;
    if (gi < 1568) {
      int t = gi >> 5, ch4 = (gi & 31) << 2;
      int tr = t / 7, tc = t - tr * 7;
      int rr = wr * 7 + tr + 3; rr -= (rr >= 56) ? 56 : 0;
      int cc = wc * 7 + tc + 3; cc -= (cc >= 56) ? 56 : 0;
      size_t off = ((size_t)b * 3136 + rr * 56 + cc) * 128 + ch4;
      f32x4 d = *(const f32x4*)&Rp[t * 128 + (ch4 ^ ((t & 7) << 2))];
      float4 xr = *(const float4*)(x + off);
      float4 ov;
      ov.x = xr.x + d[0]; ov.y = xr.y + d[1];
      ov.z = xr.z + d[2]; ov.w = xr.w + d[3];
      *(float4*)(x_new + off) = ov;
    }
  }
}

// ---------------------------------------------------------------------------
// fused MLP v6: cooperative 64-row block, 4 waves, oi-INNER MFMA1,
// DOUBLE-BUFFERED hid (LDS 48K) -> one barrier per ck, cheap sigmoid GELU.
// ---------------------------------------------------------------------------
__global__ __launch_bounds__(256, 2) void mlp_kernel(
    float* __restrict__ xio,
    const float* __restrict__ g2, const float* __restrict__ b2,
    const ushort* __restrict__ w1, const float* __restrict__ fb1,
    const ushort* __restrict__ w2, const float* __restrict__ fb2)
{
  __shared__ __align__(16) char smem[49152];   // Axs 16K | hid0 16K | hid1 16K
  char* Axs = smem;
  float* Rp = (float*)smem;                    // [64][128] fp32, aliases Axs+hid0
  const int tid = threadIdx.x, lane = tid & 63, w = tid >> 6;
  const int g = lane >> 4, li = lane & 15;
  float* xw = xio + (size_t)blockIdx.x * 64 * 128;
  const f32x4 zf = {0.f, 0.f, 0.f, 0.f};

  // ---- stage: LN2(x) -> Axs bf16 [16 chslot][64 tok][16B], tok-xor swizzle --
#pragma unroll
  for (int it = 0; it < 8; ++it) {
    int gi = it * 256 + tid;
    int row = gi >> 5, ch4 = (gi & 31) << 2;
    float4 v = *(const float4*)(xw + row * 128 + ch4);
    float s = v.x + v.y + v.z + v.w;
    float s2 = v.x*v.x + v.y*v.y + v.z*v.z + v.w*v.w;
#pragma unroll
    for (int off = 16; off; off >>= 1) { s += __shfl_xor(s, off); s2 += __shfl_xor(s2, off); }
    float mn = s * 0.0078125f;
    float rs = rsqrtf(s2 * 0.0078125f - mn * mn + 1e-5f);
    float4 gg = *(const float4*)(g2 + ch4);
    float4 bb = *(const float4*)(b2 + ch4);
    uint2 u;
    u.x = pk2((v.x - mn) * rs * gg.x + bb.x, (v.y - mn) * rs * gg.y + bb.y);
    u.y = pk2((v.z - mn) * rs * gg.z + bb.z, (v.w - mn) * rs * gg.w + bb.w);
    int slot = ch4 >> 3;
    int tokx = row ^ ((slot & 7) << 1);
    *(uint2*)(Axs + (slot * 64 + tokx) * 16 + ((ch4 & 4) << 1)) = u;
  }
  __syncthreads();                   // S0: Axs ready

  f32x4 acc2[4][2];
#pragma unroll
  for (int mi = 0; mi < 4; ++mi) { acc2[mi][0] = zf; acc2[mi][1] = zf; }

  for (int ck = 0; ck < 4; ++ck) {
    char* hls = smem + 16384 + ((ck & 1) << 14);   // double buffer
    // ---- MFMA1: hid_c[och 32 (this wave)][tok 64] = W1 slice @ LN2(x)^T ----
    f32x4 acc1[2][4];
#pragma unroll
    for (int oi = 0; oi < 2; ++oi)
#pragma unroll
      for (int mi = 0; mi < 4; ++mi) acc1[oi][mi] = zf;
#pragma unroll
    for (int kt = 0; kt < 4; ++kt) {
      const int slot = kt * 4 + g;
      short8 xf[4];
#pragma unroll
      for (int mi = 0; mi < 4; ++mi)
        xf[mi] = *(const short8*)(Axs + (slot * 64 + ((mi * 16 + li) ^ ((slot & 7) << 1))) * 16);
#pragma unroll
      for (int oi = 0; oi < 2; ++oi) {
        short8 wf = *(const short8*)(w1 + (size_t)(ck * 128 + w * 32 + oi * 16 + li) * 128 + kt * 32 + g * 8);
#pragma unroll
        for (int mi = 0; mi < 4; ++mi) acc1[oi][mi] = MFMA(wf, xf[mi], acc1[oi][mi]);
      }
    }
#pragma unroll
    for (int oi = 0; oi < 2; ++oi) {
      f32x4 b4 = *(const f32x4*)(fb1 + ck * 128 + w * 32 + oi * 16 + g * 4);
#pragma unroll
      for (int mi = 0; mi < 4; ++mi) {
        f32x4 h = acc1[oi][mi] + b4;
        uint2 u; u.x = pk2(gelu(h[0]), gelu(h[1])); u.y = pk2(gelu(h[2]), gelu(h[3]));
        *(uint2*)(hls + ((w * 4 + oi * 2 + (g >> 1)) * 64 + mi * 16 + li) * 16 + ((g & 1) << 3)) = u;
      }
    }
    __syncthreads();                 // hid chunk ready (only barrier per ck)
    // ---- MFMA2: acc2[tok 64][out 32 (this wave)] += hid_c @ W2 slice^T ----
#pragma unroll
    for (int kt = 0; kt < 4; ++kt) {
      short8 hf[4];
#pragma unroll
      for (int mi = 0; mi < 4; ++mi)
        hf[mi] = *(const short8*)(hls + ((kt * 4 + g) * 64 + mi * 16 + li) * 16);
#pragma unroll
      for (int bo = 0; bo < 2; ++bo) {
        short8 wf = *(const short8*)(w2 + (size_t)(w * 32 + bo * 16 + li) * 512 + ck * 128 + kt * 32 + g * 8);
#pragma unroll
        for (int mi = 0; mi < 4; ++mi) acc2[mi][bo] = MFMA(hf[mi], wf, acc2[mi][bo]);
      }
    }
    // next ck writes the OTHER hid buffer -> no trailing barrier needed
  }

  // ---- epilogue: fp32 repack + residual ----
#pragma unroll
  for (int mi = 0; mi < 4; ++mi)
#pragma unroll
    for (int bo = 0; bo < 2; ++bo) {
      int out = w * 32 + bo * 16 + li;
#pragma unroll
      for (int r = 0; r < 4; ++r) {
        int tok = mi * 16 + g * 4 + r;
        Rp[tok * 128 + (out ^ ((tok & 7) << 2))] = acc2[mi][bo][r];
      }
    }
  __syncthreads();                   // Rp ready
#pragma unroll
  for (int it = 0; it < 8; ++it) {
    int gi = it * 256 + tid;
    int row = gi >> 5, ch4 = (gi & 31) << 2;
    f32x4 d = *(const f32x4*)&Rp[row * 128 + (ch4 ^ ((row & 7) << 2))];
    float4 xr = *(const float4*)(xw + row * 128 + ch4);
    float4 bb = *(const float4*)(fb2 + ch4);
    float4 ov;
    ov.x = xr.x + d[0] + bb.x; ov.y = xr.y + d[1] + bb.y;
    ov.z = xr.z + d[2] + bb.z; ov.w = xr.w + d[3] + bb.w;
    *(float4*)(xw + row * 128 + ch4) = ov;
  }
}

// ---------------------------------------------------------------------------
extern "C" void kernel_launch(void* const* d_in, const int* in_sizes, int n_in,
                              void* d_out, int out_size, void* d_ws, size_t ws_size,
                              hipStream_t stream)
{
  const float* x      = (const float*)d_in[0];
  const float* g1     = (const float*)d_in[1];
  const float* b1     = (const float*)d_in[2];
  const float* qkv_w  = (const float*)d_in[3];
  const float* qkv_b  = (const float*)d_in[4];
  const float* rpb    = (const float*)d_in[5];
  const float* proj_w = (const float*)d_in[6];
  const float* proj_b = (const float*)d_in[7];
  const float* g2     = (const float*)d_in[8];
  const float* b2     = (const float*)d_in[9];
  const float* fc1_w  = (const float*)d_in[10];
  const float* fc1_b  = (const float*)d_in[11];
  const float* fc2_w  = (const float*)d_in[12];
  const float* fc2_b  = (const float*)d_in[13];

  char* ws = (char*)d_ws;
  ushort* T2b     = (ushort*)ws;                // 131072 B
  ushort* qkv_wb  = (ushort*)(ws + 262144);     // 98304
  ushort* proj_wb = (ushort*)(ws + 360448);     // 32768
  ushort* fc1_wb  = (ushort*)(ws + 393216);     // 131072
  ushort* fc2_wb  = (ushort*)(ws + 524288);     // 131072
  float*  qkv_bs  = (float*)(ws + 655360);      // 1536
  float* out = (float*)d_out;                   // x_new lives here too

  prep_kernel<<<256, 256, 0, stream>>>(qkv_w, qkv_b, rpb, proj_w, fc1_w, fc2_w,
                                       qkv_wb, qkv_bs, proj_wb, fc1_wb, fc2_wb, T2b);
  attn_kernel<<<4096, 256, 0, stream>>>(x, g1, b1, qkv_wb, qkv_bs, T2b,
                                        proj_wb, proj_b, out);
  mlp_kernel<<<3136, 256, 0, stream>>>(out, g2, b2, fc1_wb, fc1_b, fc2_wb, fc2_b);
}

// Round 18
// 305.155 us; speedup vs baseline: 1.1710x; 1.0009x over previous
//
#include <hip/hip_runtime.h>

typedef unsigned int uint;
typedef unsigned short ushort;
using short8 = __attribute__((ext_vector_type(8))) short;
using f32x4  = __attribute__((ext_vector_type(4))) float;
using uint4v = __attribute__((ext_vector_type(4))) uint;

#define SCALE_ 0.17677669529663687f
#define MFMA(a,b,c) __builtin_amdgcn_mfma_f32_16x16x32_bf16(a,b,c,0,0,0)

__device__ inline ushort f2bf(float f){
  uint u = __float_as_uint(f);
  return (ushort)((u + 0x7fffu + ((u >> 16) & 1u)) >> 16);
}
__device__ inline uint pk2(float a, float b){
  return (uint)f2bf(a) | ((uint)f2bf(b) << 16);
}
// tanh-form GELU via sigmoid: err <= ~5e-4, far below bf16-hid rounding.
__device__ inline float gelu(float v){
  return v / (1.f + __expf(-1.5957691f * (v + 0.044715f * v * v * v)));
}

// ---------------------------------------------------------------------------
// prep: bf16 weights (SCALE folded into q), scaled qkv bias, bias+mask table
// T2b[cls][h][tok][key] in BF16 (pad = -30000 so padding self-masks).
// ---------------------------------------------------------------------------
__global__ __launch_bounds__(256) void prep_kernel(
    const float* __restrict__ qkv_w, const float* __restrict__ qkv_b,
    const float* __restrict__ rpb, const float* __restrict__ proj_w,
    const float* __restrict__ fc1_w, const float* __restrict__ fc2_w,
    ushort* __restrict__ qkv_wb, float* __restrict__ qkv_bs,
    ushort* __restrict__ proj_wb, ushort* __restrict__ fc1_wb,
    ushort* __restrict__ fc2_wb, ushort* __restrict__ T2b)
{
  int i = blockIdx.x * 256 + threadIdx.x;           // 0..65535
  if (i < 49152) qkv_wb[i] = f2bf(qkv_w[i] * (i < 16384 ? SCALE_ : 1.f));
  if (i < 16384) proj_wb[i] = f2bf(proj_w[i]);
  if (i < 65536) { fc1_wb[i] = f2bf(fc1_w[i]); fc2_wb[i] = f2bf(fc2_w[i]); }
  if (i < 384)   qkv_bs[i] = qkv_b[i] * (i < 128 ? SCALE_ : 1.f);
  if (i < 65536) {
    int cls = i >> 14, h = (i >> 12) & 3, tok = (i >> 6) & 63, key = i & 63;
    float val = -30000.f;
    if (tok < 49 && key < 49) {
      int ri = tok / 7, ci = tok - ri * 7, rj = key / 7, cj = key - rj * 7;
      val = rpb[((ri - rj + 6) * 13 + (ci - cj + 6)) * 4 + h];
      int er = cls >> 1, ec = cls & 1;
      int regi = (er ? (ri < 4 ? 1 : 2) : 0) * 3 + (ec ? (ci < 4 ? 1 : 2) : 0);
      int regj = (er ? (rj < 4 ? 1 : 2) : 0) * 3 + (ec ? (cj < 4 ? 1 : 2) : 0);
      if (regi != regj) val -= 100.f;
    }
    T2b[i] = f2bf(val);
  }
}

// ---------------------------------------------------------------------------
// attn v8 (best measured): m-OUTER, kf+vt once, per-m
// {q-MFMA, scores, softmax, PV}.  T2 bf16.  LDS 25088 B.
// 4096 blocks, 256 threads, wave w = head w.
// ---------------------------------------------------------------------------
__global__ __launch_bounds__(256, 2) void attn_kernel(
    const float* __restrict__ x, const float* __restrict__ g1, const float* __restrict__ b1,
    const ushort* __restrict__ qkv_wb, const float* __restrict__ qkv_bs,
    const ushort* __restrict__ T2b, const ushort* __restrict__ proj_wb,
    const float* __restrict__ proj_b, float* __restrict__ x_new)
{
  __shared__ __align__(16) char smem[25088];
  char*   xls = smem;                 // [0,16384)  staged LN1-x (subtiled+swz)
  ushort* oa  = (ushort*)smem;        // [0,17408)  after B1 (xls dead)
  float*  Rp  = (float*)smem;         // [0,25088)  after B3 (oa dead)
  const int tid = threadIdx.x;
  const int w = tid >> 6, lane = tid & 63;
  const int g = lane >> 4, li = lane & 15;
  const int blk = blockIdx.x;
  const int b = blk >> 6, wi = blk & 63;
  const int wr = wi >> 3, wc = wi & 7;
  const float* xb = x + (size_t)b * (3136 * 128);
  const f32x4 zf = {0.f, 0.f, 0.f, 0.f};
  const int srcA = ((g & 1) << 5) + li;
  const int srcB = srcA + 16;
  const int hi = g >> 1;

  // ---- P0: coalesced shifted gather + fp32 LN1 -> xls bf16 (swizzled) ----
#pragma unroll
  for (int it = 0; it < 7; ++it) {
    int gi = it * 256 + tid;
    bool ok = gi < 1568;
    int t = ok ? (gi >> 5) : 48;
    int ch4 = (gi & 31) << 2;
    int tr = t / 7, tc = t - tr * 7;
    int rr = wr * 7 + tr + 3; rr -= (rr >= 56) ? 56 : 0;
    int cc = wc * 7 + tc + 3; cc -= (cc >= 56) ? 56 : 0;
    float4 v = *(const float4*)(xb + (size_t)(rr * 56 + cc) * 128 + ch4);
    float s = v.x + v.y + v.z + v.w;
    float s2 = v.x*v.x + v.y*v.y + v.z*v.z + v.w*v.w;
#pragma unroll
    for (int off = 16; off; off >>= 1) { s += __shfl_xor(s, off); s2 += __shfl_xor(s2, off); }
    float mn = s * 0.0078125f;
    float rs = rsqrtf(s2 * 0.0078125f - mn * mn + 1e-5f);
    if (ok) {
      float4 gg = *(const float4*)(g1 + ch4);
      float4 bb = *(const float4*)(b1 + ch4);
      uint2 u;
      u.x = pk2((v.x - mn) * rs * gg.x + bb.x, (v.y - mn) * rs * gg.y + bb.y);
      u.y = pk2((v.z - mn) * rs * gg.z + bb.z, (v.w - mn) * rs * gg.w + bb.w);
      int slot = ch4 >> 3;
      int tokx = t ^ ((slot & 7) << 1);
      *(uint2*)(xls + (slot * 64 + tokx) * 16 + ((ch4 & 4) << 1)) = u;
    }
  }
  if (tid < 240) {   // zero pad tokens 49..63
    int slot = tid & 15, t = 49 + (tid >> 4);
    int tokx = t ^ ((slot & 7) << 1);
    uint4 z = make_uint4(0u, 0u, 0u, 0u);
    *(uint4*)(xls + (slot * 64 + tokx) * 16) = z;
  }
  __syncthreads();                                  // B0: xls ready

  // ---- P1-k: k MFMA (swapped) -> kf fragments (32 acc transient) ----
  short8 kf[4];
  {
    f32x4 kacc[2][4];
#pragma unroll
    for (int cf = 0; cf < 2; ++cf)
#pragma unroll
      for (int m = 0; m < 4; ++m) kacc[cf][m] = zf;
#pragma unroll
    for (int kt = 0; kt < 4; ++kt) {
      const int slot = kt * 4 + g;
      short8 xf[4];
#pragma unroll
      for (int m = 0; m < 4; ++m)
        xf[m] = *(const short8*)(xls + (slot * 64 + ((m * 16 + li) ^ ((slot & 7) << 1))) * 16);
      const int wofs = kt * 32 + g * 8;
#pragma unroll
      for (int cf = 0; cf < 2; ++cf) {
        short8 wk = *(const short8*)(qkv_wb + (size_t)(128 + w * 32 + cf * 16 + li) * 128 + wofs);
#pragma unroll
        for (int m = 0; m < 4; ++m) kacc[cf][m] = MFMA(wk, xf[m], kacc[cf][m]);
      }
    }
    uint2 kp[2][4];
#pragma unroll
    for (int cf = 0; cf < 2; ++cf) {
      f32x4 kb4 = *(const f32x4*)(qkv_bs + 128 + w * 32 + cf * 16 + g * 4);
#pragma unroll
      for (int m = 0; m < 4; ++m) {
        f32x4 kv = kacc[cf][m] + kb4;
        kp[cf][m].x = pk2(kv[0], kv[1]); kp[cf][m].y = pk2(kv[2], kv[3]);
      }
    }
#pragma unroll
    for (int n = 0; n < 4; ++n) {
      uint a0 = __shfl(kp[0][n].x, srcA), a1 = __shfl(kp[0][n].y, srcA);
      uint a2 = __shfl(kp[0][n].x, srcB), a3 = __shfl(kp[0][n].y, srcB);
      uint b0 = __shfl(kp[1][n].x, srcA), b1 = __shfl(kp[1][n].y, srcA);
      uint b2 = __shfl(kp[1][n].x, srcB), b3 = __shfl(kp[1][n].y, srcB);
      uint4v u = { hi ? b0 : a0, hi ? b1 : a1, hi ? b2 : a2, hi ? b3 : a3 };
      kf[n] = __builtin_bit_cast(short8, u);
    }
  }

  // ---- P1-v: v MFMA -> vt A-fragments directly (32 acc transient) ----
  short8 vt[2][2];
  {
    f32x4 vacc[4][2];
#pragma unroll
    for (int m = 0; m < 4; ++m) { vacc[m][0] = zf; vacc[m][1] = zf; }
#pragma unroll
    for (int kt = 0; kt < 4; ++kt) {
      const int slot = kt * 4 + g;
      short8 xf[4];
#pragma unroll
      for (int m = 0; m < 4; ++m)
        xf[m] = *(const short8*)(xls + (slot * 64 + ((m * 16 + li) ^ ((slot & 7) << 1))) * 16);
      const int wofs = kt * 32 + g * 8;
#pragma unroll
      for (int cf = 0; cf < 2; ++cf) {
        short8 wv = *(const short8*)(qkv_wb + (size_t)(256 + w * 32 + cf * 16 + li) * 128 + wofs);
#pragma unroll
        for (int m = 0; m < 4; ++m) vacc[m][cf] = MFMA(xf[m], wv, vacc[m][cf]);
      }
    }
    uint2 vp[4][2];
#pragma unroll
    for (int cf = 0; cf < 2; ++cf) {
      float vb = qkv_bs[256 + w * 32 + cf * 16 + li];
#pragma unroll
      for (int m = 0; m < 4; ++m) {
        f32x4 vv = vacc[m][cf];
        vp[m][cf].x = pk2(vv[0] + vb, vv[1] + vb);
        vp[m][cf].y = pk2(vv[2] + vb, vv[3] + vb);
      }
    }
#pragma unroll
    for (int kt = 0; kt < 2; ++kt)
#pragma unroll
      for (int half = 0; half < 2; ++half) {
        uint a0 = __shfl(vp[kt * 2][half].x, srcA), a1 = __shfl(vp[kt * 2][half].y, srcA);
        uint a2 = __shfl(vp[kt * 2][half].x, srcB), a3 = __shfl(vp[kt * 2][half].y, srcB);
        uint b0 = __shfl(vp[kt * 2 + 1][half].x, srcA), b1 = __shfl(vp[kt * 2 + 1][half].y, srcA);
        uint b2 = __shfl(vp[kt * 2 + 1][half].x, srcB), b3 = __shfl(vp[kt * 2 + 1][half].y, srcB);
        uint4v uv = { hi ? b0 : a0, hi ? b1 : a1, hi ? b2 : a2, hi ? b3 : a3 };
        vt[kt][half] = __builtin_bit_cast(short8, uv);
      }
  }

  // ---- P2: per-m {q MFMA, scores, softmax, PV}  (small transient state) ----
  f32x4 oacc[2][4];
#pragma unroll
  for (int cf = 0; cf < 2; ++cf)
#pragma unroll
    for (int m = 0; m < 4; ++m) oacc[cf][m] = zf;
  {
    const int cls = ((wr == 7) ? 2 : 0) | ((wc == 7) ? 1 : 0);
    const ushort* Tb = T2b + ((cls * 4 + w) << 12);
    const f32x4 qb40 = *(const f32x4*)(qkv_bs + w * 32 + g * 4);
    const f32x4 qb41 = *(const f32x4*)(qkv_bs + w * 32 + 16 + g * 4);
#pragma unroll
    for (int m = 0; m < 4; ++m) {
      // q MFMA for this m only (8 acc live)
      f32x4 qacc[2] = {zf, zf};
#pragma unroll
      for (int kt = 0; kt < 4; ++kt) {
        const int slot = kt * 4 + g;
        short8 xfm = *(const short8*)(xls + (slot * 64 + ((m * 16 + li) ^ ((slot & 7) << 1))) * 16);
        const int wofs = kt * 32 + g * 8;
        short8 wq0 = *(const short8*)(qkv_wb + (size_t)(w * 32 + li) * 128 + wofs);
        short8 wq1 = *(const short8*)(qkv_wb + (size_t)(w * 32 + 16 + li) * 128 + wofs);
        qacc[0] = MFMA(wq0, xfm, qacc[0]);
        qacc[1] = MFMA(wq1, xfm, qacc[1]);
      }
      uint2 qpm[2];
      {
        f32x4 q0 = qacc[0] + qb40;
        f32x4 q1 = qacc[1] + qb41;
        qpm[0].x = pk2(q0[0], q0[1]); qpm[0].y = pk2(q0[2], q0[3]);
        qpm[1].x = pk2(q1[0], q1[1]); qpm[1].y = pk2(q1[2], q1[3]);
      }
      uint a0 = __shfl(qpm[0].x, srcA), a1 = __shfl(qpm[0].y, srcA);
      uint a2 = __shfl(qpm[0].x, srcB), a3 = __shfl(qpm[0].y, srcB);
      uint b0 = __shfl(qpm[1].x, srcA), b1 = __shfl(qpm[1].y, srcA);
      uint b2 = __shfl(qpm[1].x, srcB), b3 = __shfl(qpm[1].y, srcB);
      uint4v uq = { hi ? b0 : a0, hi ? b1 : a1, hi ? b2 : a2, hi ? b3 : a3 };
      short8 qf = __builtin_bit_cast(short8, uq);
      // scores + bf16 bias table
      f32x4 s[4];
#pragma unroll
      for (int n = 0; n < 4; ++n) {
        s[n] = MFMA(kf[n], qf, zf);
        uint2 tv = *(const uint2*)(Tb + (m * 16 + li) * 64 + n * 16 + g * 4);
        s[n][0] += __uint_as_float(tv.x << 16);
        s[n][1] += __uint_as_float(tv.x & 0xffff0000u);
        s[n][2] += __uint_as_float(tv.y << 16);
        s[n][3] += __uint_as_float(tv.y & 0xffff0000u);
      }
      // softmax (row in-thread over n, 16-lane group reduce over cols)
      float mx = -3.4e38f;
#pragma unroll
      for (int n = 0; n < 4; ++n)
        mx = fmaxf(mx, fmaxf(fmaxf(s[n][0], s[n][1]), fmaxf(s[n][2], s[n][3])));
      mx = fmaxf(mx, __shfl_xor(mx, 16));
      mx = fmaxf(mx, __shfl_xor(mx, 32));
      float sum = 0.f;
#pragma unroll
      for (int n = 0; n < 4; ++n)
#pragma unroll
        for (int r = 0; r < 4; ++r) { float e = __expf(s[n][r] - mx); s[n][r] = e; sum += e; }
      sum += __shfl_xor(sum, 16); sum += __shfl_xor(sum, 32);
      float rsm = 1.f / sum;
      uint um[4][2];
#pragma unroll
      for (int n = 0; n < 4; ++n) {
        um[n][0] = pk2(s[n][0] * rsm, s[n][1] * rsm);
        um[n][1] = pk2(s[n][2] * rsm, s[n][3] * rsm);
      }
      // PV for this m
#pragma unroll
      for (int kt = 0; kt < 2; ++kt) {
        uint t00 = __shfl(um[kt * 2][0], srcA),  t10 = __shfl(um[kt * 2 + 1][0], srcA);
        uint t01 = __shfl(um[kt * 2][1], srcA),  t11 = __shfl(um[kt * 2 + 1][1], srcA);
        uint t02 = __shfl(um[kt * 2][0], srcB),  t12 = __shfl(um[kt * 2 + 1][0], srcB);
        uint t03 = __shfl(um[kt * 2][1], srcB),  t13 = __shfl(um[kt * 2 + 1][1], srcB);
        uint4v pu = { hi ? t10 : t00, hi ? t11 : t01, hi ? t12 : t02, hi ? t13 : t03 };
        short8 pf = __builtin_bit_cast(short8, pu);
        oacc[0][m] = MFMA(vt[kt][0], pf, oacc[0][m]);
        oacc[1][m] = MFMA(vt[kt][1], pf, oacc[1][m]);
      }
    }
  }
  __syncthreads();                                  // B1: xls dead
  // attn-out -> oa[64][136] bf16 (cross-head gather for proj)
#pragma unroll
  for (int cf = 0; cf < 2; ++cf)
#pragma unroll
    for (int m = 0; m < 4; ++m) {
      uint2 ou; ou.x = pk2(oacc[cf][m][0], oacc[cf][m][1]);
      ou.y = pk2(oacc[cf][m][2], oacc[cf][m][3]);
      *(uint2*)((char*)oa + ((m * 16 + li) * 136 + w * 32 + cf * 16 + g * 4) * 2) = ou;
    }
  __syncthreads();                                  // B2: oa ready

  // ---- P3: proj MFMA (wave w owns out-ch [32w,32w+32)) ----
  f32x4 pacc[2][4];
#pragma unroll
  for (int cf = 0; cf < 2; ++cf)
#pragma unroll
    for (int m = 0; m < 4; ++m) pacc[cf][m] = zf;
#pragma unroll
  for (int kt = 0; kt < 4; ++kt) {
    short8 af[4];
#pragma unroll
    for (int m = 0; m < 4; ++m)
      af[m] = *(const short8*)((char*)oa + (m * 16 + li) * 272 + kt * 64 + g * 16);
#pragma unroll
    for (int cf = 0; cf < 2; ++cf) {
      short8 wp = *(const short8*)(proj_wb + (size_t)(w * 32 + cf * 16 + li) * 128 + kt * 32 + g * 8);
#pragma unroll
      for (int m = 0; m < 4; ++m) pacc[cf][m] = MFMA(af[m], wp, pacc[cf][m]);
    }
  }
  __syncthreads();                                  // B3: oa reads done
#pragma unroll
  for (int cf = 0; cf < 2; ++cf) {
    int col = w * 32 + cf * 16 + li;
    float pb = proj_b[col];
#pragma unroll
    for (int m = 0; m < 4; ++m)
#pragma unroll
      for (int r = 0; r < 4; ++r) {
        int t2 = m * 16 + g * 4 + r;
        if (t2 < 49)
          Rp[t2 * 128 + (col ^ ((t2 & 7) << 2))] = pacc[cf][m][r] + pb;
      }
  }
  __syncthreads();                                  // B4: Rp ready

  // ---- P4: coalesced residual epilogue ----
#pragma unroll
  for (int it = 0; it < 7; ++it) {
    int gi = it * 256 + tid;
    if (gi < 1568) {
      int t = gi >> 5, ch4 = (gi & 31) << 2;
      int tr = t / 7, tc = t - tr * 7;
      int rr = wr * 7 + tr + 3; rr -= (rr >= 56) ? 56 : 0;
      int cc = wc * 7 + tc + 3; cc -= (cc >= 56) ? 56 : 0;
      size_t off = ((size_t)b * 3136 + rr * 56 + cc) * 128 + ch4;
      f32x4 d = *(const f32x4*)&Rp[t * 128 + (ch4 ^ ((t & 7) << 2))];
      float4 xr = *(const float4*)(x + off);
      float4 ov;
      ov.x = xr.x + d[0]; ov.y = xr.y + d[1];
      ov.z = xr.z + d[2]; ov.w = xr.w + d[3];
      *(float4*)(x_new + off) = ov;
    }
  }
}

// ---------------------------------------------------------------------------
// fused MLP v6: cooperative 64-row block, 4 waves, oi-INNER MFMA1,
// DOUBLE-BUFFERED hid (LDS 48K) -> one barrier per ck, cheap sigmoid GELU.
// ---------------------------------------------------------------------------
__global__ __launch_bounds__(256, 2) void mlp_kernel(
    float* __restrict__ xio,
    const float* __restrict__ g2, const float* __restrict__ b2,
    const ushort* __restrict__ w1, const float* __restrict__ fb1,
    const ushort* __restrict__ w2, const float* __restrict__ fb2)
{
  __shared__ __align__(16) char smem[49152];   // Axs 16K | hid0 16K | hid1 16K
  char* Axs = smem;
  float* Rp = (float*)smem;                    // [64][128] fp32, aliases Axs+hid0
  const int tid = threadIdx.x, lane = tid & 63, w = tid >> 6;
  const int g = lane >> 4, li = lane & 15;
  float* xw = xio + (size_t)blockIdx.x * 64 * 128;
  const f32x4 zf = {0.f, 0.f, 0.f, 0.f};

  // ---- stage: LN2(x) -> Axs bf16 [16 chslot][64 tok][16B], tok-xor swizzle --
#pragma unroll
  for (int it = 0; it < 8; ++it) {
    int gi = it * 256 + tid;
    int row = gi >> 5, ch4 = (gi & 31) << 2;
    float4 v = *(const float4*)(xw + row * 128 + ch4);
    float s = v.x + v.y + v.z + v.w;
    float s2 = v.x*v.x + v.y*v.y + v.z*v.z + v.w*v.w;
#pragma unroll
    for (int off = 16; off; off >>= 1) { s += __shfl_xor(s, off); s2 += __shfl_xor(s2, off); }
    float mn = s * 0.0078125f;
    float rs = rsqrtf(s2 * 0.0078125f - mn * mn + 1e-5f);
    float4 gg = *(const float4*)(g2 + ch4);
    float4 bb = *(const float4*)(b2 + ch4);
    uint2 u;
    u.x = pk2((v.x - mn) * rs * gg.x + bb.x, (v.y - mn) * rs * gg.y + bb.y);
    u.y = pk2((v.z - mn) * rs * gg.z + bb.z, (v.w - mn) * rs * gg.w + bb.w);
    int slot = ch4 >> 3;
    int tokx = row ^ ((slot & 7) << 1);
    *(uint2*)(Axs + (slot * 64 + tokx) * 16 + ((ch4 & 4) << 1)) = u;
  }
  __syncthreads();                   // S0: Axs ready

  f32x4 acc2[4][2];
#pragma unroll
  for (int mi = 0; mi < 4; ++mi) { acc2[mi][0] = zf; acc2[mi][1] = zf; }

  for (int ck = 0; ck < 4; ++ck) {
    char* hls = smem + 16384 + ((ck & 1) << 14);   // double buffer
    // ---- MFMA1: hid_c[och 32 (this wave)][tok 64] = W1 slice @ LN2(x)^T ----
    f32x4 acc1[2][4];
#pragma unroll
    for (int oi = 0; oi < 2; ++oi)
#pragma unroll
      for (int mi = 0; mi < 4; ++mi) acc1[oi][mi] = zf;
#pragma unroll
    for (int kt = 0; kt < 4; ++kt) {
      const int slot = kt * 4 + g;
      short8 xf[4];
#pragma unroll
      for (int mi = 0; mi < 4; ++mi)
        xf[mi] = *(const short8*)(Axs + (slot * 64 + ((mi * 16 + li) ^ ((slot & 7) << 1))) * 16);
#pragma unroll
      for (int oi = 0; oi < 2; ++oi) {
        short8 wf = *(const short8*)(w1 + (size_t)(ck * 128 + w * 32 + oi * 16 + li) * 128 + kt * 32 + g * 8);
#pragma unroll
        for (int mi = 0; mi < 4; ++mi) acc1[oi][mi] = MFMA(wf, xf[mi], acc1[oi][mi]);
      }
    }
#pragma unroll
    for (int oi = 0; oi < 2; ++oi) {
      f32x4 b4 = *(const f32x4*)(fb1 + ck * 128 + w * 32 + oi * 16 + g * 4);
#pragma unroll
      for (int mi = 0; mi < 4; ++mi) {
        f32x4 h = acc1[oi][mi] + b4;
        uint2 u; u.x = pk2(gelu(h[0]), gelu(h[1])); u.y = pk2(gelu(h[2]), gelu(h[3]));
        *(uint2*)(hls + ((w * 4 + oi * 2 + (g >> 1)) * 64 + mi * 16 + li) * 16 + ((g & 1) << 3)) = u;
      }
    }
    __syncthreads();                 // hid chunk ready (only barrier per ck)
    // ---- MFMA2: acc2[tok 64][out 32 (this wave)] += hid_c @ W2 slice^T ----
#pragma unroll
    for (int kt = 0; kt < 4; ++kt) {
      short8 hf[4];
#pragma unroll
      for (int mi = 0; mi < 4; ++mi)
        hf[mi] = *(const short8*)(hls + ((kt * 4 + g) * 64 + mi * 16 + li) * 16);
#pragma unroll
      for (int bo = 0; bo < 2; ++bo) {
        short8 wf = *(const short8*)(w2 + (size_t)(w * 32 + bo * 16 + li) * 512 + ck * 128 + kt * 32 + g * 8);
#pragma unroll
        for (int mi = 0; mi < 4; ++mi) acc2[mi][bo] = MFMA(hf[mi], wf, acc2[mi][bo]);
      }
    }
    // next ck writes the OTHER hid buffer -> no trailing barrier needed
  }

  // ---- epilogue: fp32 repack + residual ----
#pragma unroll
  for (int mi = 0; mi < 4; ++mi)
#pragma unroll
    for (int bo = 0; bo < 2; ++bo) {
      int out = w * 32 + bo * 16 + li;
#pragma unroll
      for (int r = 0; r < 4; ++r) {
        int tok = mi * 16 + g * 4 + r;
        Rp[tok * 128 + (out ^ ((tok & 7) << 2))] = acc2[mi][bo][r];
      }
    }
  __syncthreads();                   // Rp ready
#pragma unroll
  for (int it = 0; it < 8; ++it) {
    int gi = it * 256 + tid;
    int row = gi >> 5, ch4 = (gi & 31) << 2;
    f32x4 d = *(const f32x4*)&Rp[row * 128 + (ch4 ^ ((row & 7) << 2))];
    float4 xr = *(const float4*)(xw + row * 128 + ch4);
    float4 bb = *(const float4*)(fb2 + ch4);
    float4 ov;
    ov.x = xr.x + d[0] + bb.x; ov.y = xr.y + d[1] + bb.y;
    ov.z = xr.z + d[2] + bb.z; ov.w = xr.w + d[3] + bb.w;
    *(float4*)(xw + row * 128 + ch4) = ov;
  }
}

// ---------------------------------------------------------------------------
extern "C" void kernel_launch(void* const* d_in, const int* in_sizes, int n_in,
                              void* d_out, int out_size, void* d_ws, size_t ws_size,
                              hipStream_t stream)
{
  const float* x      = (const float*)d_in[0];
  const float* g1     = (const float*)d_in[1];
  const float* b1     = (const float*)d_in[2];
  const float* qkv_w  = (const float*)d_in[3];
  const float* qkv_b  = (const float*)d_in[4];
  const float* rpb    = (const float*)d_in[5];
  const float* proj_w = (const float*)d_in[6];
  const float* proj_b = (const float*)d_in[7];
  const float* g2     = (const float*)d_in[8];
  const float* b2     = (const float*)d_in[9];
  const float* fc1_w  = (const float*)d_in[10];
  const float* fc1_b  = (const float*)d_in[11];
  const float* fc2_w  = (const float*)d_in[12];
  const float* fc2_b  = (const float*)d_in[13];

  char* ws = (char*)d_ws;
  ushort* T2b     = (ushort*)ws;                // 131072 B
  ushort* qkv_wb  = (ushort*)(ws + 262144);     // 98304
  ushort* proj_wb = (ushort*)(ws + 360448);     // 32768
  ushort* fc1_wb  = (ushort*)(ws + 393216);     // 131072
  ushort* fc2_wb  = (ushort*)(ws + 524288);     // 131072
  float*  qkv_bs  = (float*)(ws + 655360);      // 1536
  float* out = (float*)d_out;                   // x_new lives here too

  prep_kernel<<<256, 256, 0, stream>>>(qkv_w, qkv_b, rpb, proj_w, fc1_w, fc2_w,
                                       qkv_wb, qkv_bs, proj_wb, fc1_wb, fc2_wb, T2b);
  attn_kernel<<<4096, 256, 0, stream>>>(x, g1, b1, qkv_wb, qkv_bs, T2b,
                                        proj_wb, proj_b, out);
  mlp_kernel<<<3136, 256, 0, stream>>>(out, g2, b2, fc1_wb, fc1_b, fc2_wb, fc2_b);
}